// Round 7
// baseline (311.112 us; speedup 1.0000x reference)
//
#include <hip/hip_runtime.h>
#include <hip/hip_bf16.h>
#include <stdint.h>

typedef __bf16 bf16x8 __attribute__((ext_vector_type(8)));
typedef float f32x4 __attribute__((ext_vector_type(4)));
typedef float f32x16 __attribute__((ext_vector_type(16)));
typedef uint32_t u32x4 __attribute__((ext_vector_type(4)));
typedef unsigned short ushort_t;
typedef unsigned short ushort8v __attribute__((ext_vector_type(8)));

#define MFMA16 __builtin_amdgcn_mfma_f32_16x16x32_bf16
#define MFMA32 __builtin_amdgcn_mfma_f32_32x32x16_bf16

static constexpr int Bc = 2, Sc = 2048, Ec = 2048, Hc = 16;

__device__ __forceinline__ void gload16(const void* g, void* l) {
  __builtin_amdgcn_global_load_lds(
      (const __attribute__((address_space(1))) void*)g,
      (__attribute__((address_space(3))) void*)l, 16, 0, 0);
}

__device__ __forceinline__ ushort_t f2bf(float f) {
  uint32_t u = __float_as_uint(f);
  uint32_t r = (u + 0x7fffu + ((u >> 16) & 1u)) >> 16;
  return (ushort_t)r;
}
__device__ __forceinline__ float bf2f(ushort_t u) {
  return __uint_as_float((uint32_t)u << 16);
}
__device__ __forceinline__ uint32_t cvtpk(float a, float b) {
  uint32_t d;
  asm("v_cvt_pk_bf16_f32 %0, %1, %2" : "=v"(d) : "v"(a), "v"(b));
  return d;
}
// exchange: a[lanes 32..63] <-> b[lanes 0..31]
__device__ __forceinline__ void plswap(uint32_t& a, uint32_t& b) {
  asm("v_permlane32_swap_b32 %0, %1" : "+v"(a), "+v"(b));
}

// ---------------- fused casts: all 5 weight/x tensors in one launch ----------------
__global__ void cast_all(const float* __restrict__ x, const float* __restrict__ Wq,
                         const float* __restrict__ Wkvu, const float* __restrict__ Wout,
                         const float* __restrict__ Wkvd,
                         ushort_t* __restrict__ xb, ushort_t* __restrict__ wq,
                         ushort_t* __restrict__ wkvu, ushort_t* __restrict__ wout,
                         ushort_t* __restrict__ wkvd) {
  int i = blockIdx.x * 256 + threadIdx.x;
  const float* src;
  ushort_t* dst;
  int j;
  if (i < 2097152) { src = x; dst = xb; j = i; }
  else if (i < 3145728) { src = Wq; dst = wq; j = i - 2097152; }
  else if (i < 3538944) { src = Wkvu; dst = wkvu; j = i - 3145728; }
  else if (i < 4587520) { src = Wout; dst = wout; j = i - 3538944; }
  else {
    j = i - 4587520;                      // wkvd with row pad 576->640
    int row = j >> 9, col4 = j & 511;
    ushort4 o;
    if (row < 576) {
      float4 v = ((const float4*)Wkvd)[row * 512 + col4];
      o.x = f2bf(v.x); o.y = f2bf(v.y); o.z = f2bf(v.z); o.w = f2bf(v.w);
    } else { o.x = 0; o.y = 0; o.z = 0; o.w = 0; }
    ((ushort4*)wkvd)[j] = o;
    return;
  }
  float4 v = ((const float4*)src)[j];
  ushort4 o;
  o.x = f2bf(v.x); o.y = f2bf(v.y); o.z = f2bf(v.z); o.w = f2bf(v.w);
  ((ushort4*)dst)[j] = o;
}

// ---------------- mask rearrange for 32x32 swapped layout ----------------
// ushort8 unit index u = q*256 + kt*8 + kblk*4 + half*2 + rr
// element j: value = mask[q][kt*64 + kblk*32 + 4*half + (j&3) + 8*(2*rr+(j>>2))] / ln2
__global__ void mask_rearrange(const float* __restrict__ mask, ushort_t* __restrict__ m4) {
  const float INVLN2 = 1.4426950408889634f;
  int i = blockIdx.x * 256 + threadIdx.x;   // 524288 units
  if (i >= 524288) return;
  int rr = i & 1, half = (i >> 1) & 1, kblk = (i >> 2) & 1, kt = (i >> 3) & 31, q = i >> 8;
  const float* src = mask + (size_t)q * 2048 + kt * 64 + kblk * 32 + half * 4 + rr * 16;
  float4 a = *(const float4*)src;         // j=0..3
  float4 c = *(const float4*)(src + 8);   // j=4..7
  ushort8v o;
  o[0] = f2bf(a.x * INVLN2); o[1] = f2bf(a.y * INVLN2);
  o[2] = f2bf(a.z * INVLN2); o[3] = f2bf(a.w * INVLN2);
  o[4] = f2bf(c.x * INVLN2); o[5] = f2bf(c.y * INVLN2);
  o[6] = f2bf(c.z * INVLN2); o[7] = f2bf(c.w * INVLN2);
  ((ushort8v*)m4)[i] = o;
}

// ---------------- GEMM: C[m][n] = sum_k A[m][k]*B[n][k], 128x128x32 tiles ----------------
template<int MODE>
__global__ __launch_bounds__(256, 2)
void gemm_bt(const ushort_t* __restrict__ A, int lda,
             const ushort_t* __restrict__ Bm, int ldb,
             void* __restrict__ Cout, int ldc,
             int M, int N, int K,
             char* __restrict__ vtb, char* __restrict__ kbuf)
{
  __shared__ __align__(16) ushort_t sA[128 * 32];
  __shared__ __align__(16) ushort_t sB[128 * 32];
  int tid = threadIdx.x;
  int nTn = N >> 7;
  int bid = blockIdx.x;
  int chunk = gridDim.x >> 3;                       // grids are %8==0 -> bijective
  bid = (bid & 7) * chunk + (bid >> 3);             // XCD-chunked swizzle
  int tm = bid / nTn, tn = bid - tm * nTn;
  int wave = tid >> 6, lane = tid & 63;
  int wm = (wave >> 1) << 6, wn = (wave & 1) << 6;
  int l16 = lane & 15, g16 = lane >> 4;
  f32x4 acc[4][4] = {};
  int srow = tid >> 2, scol = (tid & 3) << 3;
  const ushort_t* Ag = A + (size_t)(tm * 128 + srow) * lda + scol;
  const ushort_t* Bg = Bm + (size_t)(tn * 128 + srow) * ldb + scol;
  ushort_t* sAp = &sA[srow * 32 + scol];
  ushort_t* sBp = &sB[srow * 32 + scol];
  for (int kt = 0; kt < K; kt += 32) {
    gload16(Ag, sAp);
    gload16(Ag + (size_t)64 * lda, sAp + 64 * 32);
    gload16(Bg, sBp);
    gload16(Bg + (size_t)64 * ldb, sBp + 64 * 32);
    Ag += 32; Bg += 32;
    __syncthreads();
    bf16x8 af[4], bfr[4];
#pragma unroll
    for (int i = 0; i < 4; i++) af[i] = *(const bf16x8*)&sA[(wm + i * 16 + l16) * 32 + g16 * 8];
#pragma unroll
    for (int i = 0; i < 4; i++) bfr[i] = *(const bf16x8*)&sB[(wn + i * 16 + l16) * 32 + g16 * 8];
#pragma unroll
    for (int i = 0; i < 4; i++)
#pragma unroll
      for (int j = 0; j < 4; j++)
        acc[i][j] = MFMA16(af[i], bfr[j], acc[i][j], 0, 0, 0);
    __syncthreads();
  }
  // epilogue: C/D layout col=lane&15, row=(lane>>4)*4+r
#pragma unroll
  for (int i = 0; i < 4; i++) {
#pragma unroll
    for (int j = 0; j < 4; j++) {
#pragma unroll
      for (int r = 0; r < 4; r++) {
        int grow = tm * 128 + wm + i * 16 + g16 * 4 + r;
        int gcol = tn * 128 + wn + j * 16 + l16;
        float v = acc[i][j][r];
        if constexpr (MODE == 0) {
          ((ushort_t*)Cout)[(size_t)grow * ldc + gcol] = f2bf(v);
        } else if constexpr (MODE == 2) {
          ((float*)Cout)[(size_t)grow * ldc + gcol] = v;
        } else {
          int h = gcol / 192, jj = gcol - h * 192;
          int b = grow >> 11, s = grow & 2047;
          size_t bh = (size_t)(b * Hc + h);
          if (jj < 128) {
            // V^T, pre-swizzled for linear staging of 64-col tiles
            *(ushort_t*)(vtb + bh * 524288 + (size_t)jj * 4096 + ((s >> 6) * 128) +
                         ((2 * (s & 63)) ^ ((jj & 7) << 4))) = f2bf(v);
          } else {
            int col = 64 + (jj - 128);                    // nope -> k dims 64..127
            *(ushort_t*)(kbuf + (bh * Sc + s) * 256 + ((2 * col) ^ ((s & 7) << 4))) = f2bf(v);
          }
        }
      }
    }
  }
}

// ---------------- broadcast k_rope into kbuf (swizzled byte layout) ----------------
__global__ void rope_fill(const ushort_t* __restrict__ comp, char* __restrict__ kbuf) {
  int i = blockIdx.x * 256 + threadIdx.x;  // over B*S*8 16-byte blocks
  if (i >= Bc * Sc * 8) return;
  int blk = i & 7;
  int m = i >> 3;
  int s = m & 2047, b = m >> 11;
  uint4 v = *(const uint4*)&comp[(size_t)m * 640 + 512 + blk * 8];
  int off = (blk * 16) ^ ((s & 7) << 4);
#pragma unroll
  for (int h = 0; h < Hc; h++) {
    *(uint4*)(kbuf + ((size_t)(b * Hc + h) * Sc + s) * 256 + off) = v;
  }
}

// ---------------- flash attention, 32x32 MFMA, in-register P, LDS double-buffer ----------------
// block = 128 threads = 2 waves x 32 q-rows (q-tile 64); KVBLK=64; LDS 64KB (2 bufs).
// 2-phase pipeline: STAGE(t+1, other buf) issued before COMPUTE(t); 1 barrier/tile.
__global__ __launch_bounds__(128, 2)
void attn_kernel(const ushort_t* __restrict__ qb, const char* __restrict__ kbuf,
                 const char* __restrict__ vtb, const ushort_t* __restrict__ m4,
                 ushort_t* __restrict__ attn_o)
{
  __shared__ __align__(16) char smem[65536];
  char* sKA = smem;             // buf A: K 16KB
  char* sVA = smem + 16384;     //        V 16KB
  char* sKB = smem + 32768;     // buf B: K 16KB
  char* sVB = smem + 49152;     //        V 16KB
  const float scale2 = 0.12752081738040466f;  // 128^-0.5 / ln2
  int bid = blockIdx.x;
  bid = (bid & 7) * 128 + (bid >> 3);        // XCD-chunked swizzle (1024 % 8 == 0)
  int qt = bid & 31, bh = bid >> 5;
  int b = bh >> 4, h = bh & 15;
  int tid = threadIdx.x, wave = tid >> 6, lane = tid & 63;
  int l32 = lane & 31, half = lane >> 5;
  int sx = (l32 & 7) << 4;
  int qbase = qt * 64 + wave * 32;

  // Q fragments (B-operand): col = q = l32, k = ks*16 + half*8 + e
  bf16x8 qf[8];
  {
    const ushort_t* qp = qb + (size_t)(b * Sc + qbase + l32) * 2048 + h * 128 + half * 8;
#pragma unroll
    for (int ks = 0; ks < 8; ks++) qf[ks] = *(const bf16x8*)(qp + ks * 16);
  }

  float mrun = -3.0e38f, lrun = 0.f;   // per-lane scalars for q = qbase + l32
  f32x16 acco[4] = {};                  // [vdblk]; rows = q reg-pattern, col = vd

  const char* kg = kbuf + (size_t)bh * 524288;
  const char* vg = vtb + (size_t)bh * 524288;
  const ushort8v* mq = (const ushort8v*)m4 + (size_t)(qbase + l32) * 256 + half * 2;

  auto STAGE = [&](int kt, char* sKb, char* sVb) {
#pragma unroll
    for (int it = 0; it < 8; it++)
      gload16(kg + kt * 16384 + it * 2048 + tid * 16, sKb + it * 2048 + tid * 16);
#pragma unroll
    for (int it = 0; it < 8; it++) {
      int l = it * 2048 + tid * 16;
      gload16(vg + (size_t)(l >> 7) * 4096 + kt * 128 + (l & 127), sVb + l);
    }
  };

  auto COMPUTE = [&](int kt, const char* sKb, const char* sVb) {
    // mask fragments (4 x 16B global loads; latency hides under QK^T)
    ushort8v mvv[4];
#pragma unroll
    for (int kb = 0; kb < 2; kb++)
#pragma unroll
      for (int rr = 0; rr < 2; rr++)
        mvv[kb * 2 + rr] = mq[kt * 8 + kb * 4 + rr];

    // QK^T (swapped), both kblks interleaved -> 2 independent MFMA chains
    f32x16 sc0 = {}, sc1 = {};
    __builtin_amdgcn_s_setprio(1);
#pragma unroll
    for (int ks = 0; ks < 8; ks++) {
      bf16x8 k0 = *(const bf16x8*)(sKb + l32 * 256 + ((ks * 32 + half * 16) ^ sx));
      bf16x8 k1 = *(const bf16x8*)(sKb + (32 + l32) * 256 + ((ks * 32 + half * 16) ^ sx));
      sc0 = MFMA32(k0, qf[ks], sc0, 0, 0, 0);
      sc1 = MFMA32(k1, qf[ks], sc1, 0, 0, 0);
    }
    __builtin_amdgcn_s_setprio(0);

    // lane-local softmax over 32 scores (q = l32; k = (r&3)+8*(r>>2)+4*half + kblk*32)
#pragma unroll
    for (int r = 0; r < 16; r++) {
      sc0[r] = sc0[r] * scale2 + bf2f(mvv[r >> 3][r & 7]);
      sc1[r] = sc1[r] * scale2 + bf2f(mvv[2 + (r >> 3)][r & 7]);
    }
    float mx = fmaxf(sc0[0], sc1[0]);
#pragma unroll
    for (int r = 1; r < 16; r++) mx = fmaxf(mx, fmaxf(sc0[r], sc1[r]));
    mx = fmaxf(mx, __shfl_xor(mx, 32));
    if (!__all(mx <= mrun + 11.0f)) {       // T13 defer-max (rare)
      float mnew = fmaxf(mrun, mx);
      float corr = __builtin_amdgcn_exp2f(mrun - mnew);
      lrun *= corr; mrun = mnew;
#pragma unroll
      for (int r = 0; r < 16; r++) {
        float cr = __shfl(corr, (r & 3) + 8 * (r >> 2) + 4 * half);
#pragma unroll
        for (int vb = 0; vb < 4; vb++) acco[vb][r] *= cr;
      }
    }
    float rs = 0.f;
    uint32_t W0[8], W1[8];
#pragma unroll
    for (int m = 0; m < 4; m++) {
      float a0 = __builtin_amdgcn_exp2f(sc0[4 * m + 0] - mrun);
      float a1 = __builtin_amdgcn_exp2f(sc0[4 * m + 1] - mrun);
      float a2 = __builtin_amdgcn_exp2f(sc0[4 * m + 2] - mrun);
      float a3 = __builtin_amdgcn_exp2f(sc0[4 * m + 3] - mrun);
      float b0 = __builtin_amdgcn_exp2f(sc1[4 * m + 0] - mrun);
      float b1 = __builtin_amdgcn_exp2f(sc1[4 * m + 1] - mrun);
      float b2 = __builtin_amdgcn_exp2f(sc1[4 * m + 2] - mrun);
      float b3 = __builtin_amdgcn_exp2f(sc1[4 * m + 3] - mrun);
      rs += (a0 + a1) + (a2 + a3) + (b0 + b1) + (b2 + b3);
      W0[2 * m] = cvtpk(a0, a1); W0[2 * m + 1] = cvtpk(a2, a3);
      W1[2 * m] = cvtpk(b0, b1); W1[2 * m + 1] = cvtpk(b2, b3);
    }
    lrun += rs;   // lane-partial (this half's k); combined in epilogue

    // redistribute P to PV A-frag layout via permlane32_swap
    bf16x8 pf0[2], pf1[2];
#pragma unroll
    for (int k2 = 0; k2 < 2; k2++) {
      {
        uint32_t a0 = W0[4 * k2 + 0], a1 = W0[4 * k2 + 1];
        uint32_t b0 = W0[4 * k2 + 2], b1 = W0[4 * k2 + 3];
        plswap(a0, b0); plswap(a1, b1);
        u32x4 t; t[0] = a0; t[1] = a1; t[2] = b0; t[3] = b1;
        pf0[k2] = __builtin_bit_cast(bf16x8, t);
      }
      {
        uint32_t a0 = W1[4 * k2 + 0], a1 = W1[4 * k2 + 1];
        uint32_t b0 = W1[4 * k2 + 2], b1 = W1[4 * k2 + 3];
        plswap(a0, b0); plswap(a1, b1);
        u32x4 t; t[0] = a0; t[1] = a1; t[2] = b0; t[3] = b1;
        pf1[k2] = __builtin_bit_cast(bf16x8, t);
      }
    }

    // PV: acco[vb] += P(32q x 64k) . V(64k x 128vd) -- 4 independent chains
    __builtin_amdgcn_s_setprio(1);
#pragma unroll
    for (int k2 = 0; k2 < 2; k2++) {
#pragma unroll
      for (int vb = 0; vb < 4; vb++) {
        bf16x8 vf = *(const bf16x8*)(sVb + (vb * 32 + l32) * 128 +
                                     ((k2 * 32 + half * 16) ^ sx));
        acco[vb] = MFMA32(pf0[k2], vf, acco[vb], 0, 0, 0);
      }
#pragma unroll
      for (int vb = 0; vb < 4; vb++) {
        bf16x8 vf = *(const bf16x8*)(sVb + (vb * 32 + l32) * 128 +
                                     ((64 + k2 * 32 + half * 16) ^ sx));
        acco[vb] = MFMA32(pf1[k2], vf, acco[vb], 0, 0, 0);
      }
    }
    __builtin_amdgcn_s_setprio(0);
  };

  // 2-phase pipeline, unroll-by-2 for static buffer bases
  STAGE(0, sKA, sVA);
  __syncthreads();
  for (int kt = 0; kt < 32; kt += 2) {
    STAGE(kt + 1, sKB, sVB);
    COMPUTE(kt, sKA, sVA);
    __syncthreads();
    if (kt + 2 < 32) STAGE(kt + 2, sKA, sVA);
    COMPUTE(kt + 1, sKB, sVB);
    __syncthreads();
  }

  // epilogue: combine half-partial l, divide, store
  lrun += __shfl_xor(lrun, 32);
#pragma unroll
  for (int r = 0; r < 16; r++) {
    int rowq = (r & 3) + 8 * (r >> 2) + 4 * half;
    float lr = __shfl(lrun, rowq);
    float inv = 1.0f / lr;
    int qrow = qbase + rowq;
    ushort_t* op = attn_o + (size_t)(b * Sc + qrow) * 2048 + h * 128 + l32;
#pragma unroll
    for (int vb = 0; vb < 4; vb++)
      op[vb * 32] = f2bf(acco[vb][r] * inv);
  }
}

extern "C" void kernel_launch(void* const* d_in, const int* in_sizes, int n_in,
                              void* d_out, int out_size, void* d_ws, size_t ws_size,
                              hipStream_t stream) {
  const float* x    = (const float*)d_in[0];
  const float* mask = (const float*)d_in[1];
  const float* Wkvd = (const float*)d_in[2];
  const float* Wkvu = (const float*)d_in[3];
  const float* Wq   = (const float*)d_in[4];
  const float* Wout = (const float*)d_in[5];

  char* ws = (char*)d_ws;
  size_t off = 0;
  auto alloc = [&](size_t bytes) { char* p = ws + off; off += (bytes + 255) & ~(size_t)255; return p; };
  ushort_t* xb   = (ushort_t*)alloc((size_t)4096 * 2048 * 2);
  ushort_t* wkvd = (ushort_t*)alloc((size_t)640 * 2048 * 2);
  ushort_t* wq   = (ushort_t*)alloc((size_t)2048 * 2048 * 2);
  ushort_t* wkvu = (ushort_t*)alloc((size_t)3072 * 512 * 2);
  ushort_t* wout = (ushort_t*)alloc((size_t)2048 * 2048 * 2);
  ushort_t* comp = (ushort_t*)alloc((size_t)4096 * 640 * 2);
  ushort_t* qbuf = (ushort_t*)alloc((size_t)4096 * 2048 * 2);
  char*     kbuf = alloc((size_t)Bc * Hc * Sc * 256);
  char*     vtb  = alloc((size_t)Bc * Hc * 524288);
  ushort_t* attn_o = xb;   // xb dead after q-GEMM; reuse
  ushort_t* m4 = wq;       // wq dead after q-GEMM; reuse (8MB)

  // all casts in one launch
  cast_all<<<19200, 256, 0, stream>>>(x, Wq, Wkvu, Wout, Wkvd, xb, wq, wkvu, wout, wkvd);

  // compressed = x . W_kv_down^T  (N padded 576->640)
  gemm_bt<0><<<32 * 5, 256, 0, stream>>>(xb, 2048, wkvd, 2048, comp, 640, 4096, 640, 2048, nullptr, nullptr);
  // q = x . W_q^T
  gemm_bt<0><<<32 * 16, 256, 0, stream>>>(xb, 2048, wq, 2048, qbuf, 2048, 4096, 2048, 2048, nullptr, nullptr);
  // mask -> 32x32 swapped fragment order bf16 * (1/ln2)  (after q-GEMM: m4 overlays wq)
  mask_rearrange<<<2048, 256, 0, stream>>>(mask, m4);
  // kv_exp = kv_c . W_kv_up^T, scattered into vT(swizzled) + kbuf(nope, swizzled)
  gemm_bt<1><<<32 * 24, 256, 0, stream>>>(comp, 640, wkvu, 512, nullptr, 0, 4096, 3072, 512, vtb, kbuf);
  // k_rope broadcast into kbuf (swizzled)
  rope_fill<<<32768 / 256, 256, 0, stream>>>(comp, kbuf);
  // flash attention (32x32 MFMA, in-register P, double-buffered 2-phase)
  attn_kernel<<<1024, 128, 0, stream>>>(qbuf, kbuf, vtb, m4, attn_o);
  // out = attn . W_out^T (fp32 store)
  gemm_bt<2><<<32 * 16, 256, 0, stream>>>(attn_o, 2048, wout, 2048, d_out, 2048, 4096, 2048, 2048, nullptr, nullptr);
}

// Round 8
// 299.541 us; speedup vs baseline: 1.0386x; 1.0386x over previous
//
#include <hip/hip_runtime.h>
#include <hip/hip_bf16.h>
#include <stdint.h>

typedef __bf16 bf16x8 __attribute__((ext_vector_type(8)));
typedef float f32x4 __attribute__((ext_vector_type(4)));
typedef float f32x16 __attribute__((ext_vector_type(16)));
typedef uint32_t u32x4 __attribute__((ext_vector_type(4)));
typedef unsigned short ushort_t;
typedef unsigned short ushort8v __attribute__((ext_vector_type(8)));

#define MFMA16 __builtin_amdgcn_mfma_f32_16x16x32_bf16
#define MFMA32 __builtin_amdgcn_mfma_f32_32x32x16_bf16

static constexpr int Bc = 2, Sc = 2048, Ec = 2048, Hc = 16;

__device__ __forceinline__ void gload16(const void* g, void* l) {
  __builtin_amdgcn_global_load_lds(
      (const __attribute__((address_space(1))) void*)g,
      (__attribute__((address_space(3))) void*)l, 16, 0, 0);
}

__device__ __forceinline__ ushort_t f2bf(float f) {
  uint32_t u = __float_as_uint(f);
  uint32_t r = (u + 0x7fffu + ((u >> 16) & 1u)) >> 16;
  return (ushort_t)r;
}
__device__ __forceinline__ float bf2f(ushort_t u) {
  return __uint_as_float((uint32_t)u << 16);
}
__device__ __forceinline__ uint32_t cvtpk(float a, float b) {
  uint32_t d;
  asm("v_cvt_pk_bf16_f32 %0, %1, %2" : "=v"(d) : "v"(a), "v"(b));
  return d;
}
// exchange: a[lanes 32..63] <-> b[lanes 0..31]
__device__ __forceinline__ void plswap(uint32_t& a, uint32_t& b) {
  asm("v_permlane32_swap_b32 %0, %1" : "+v"(a), "+v"(b));
}

// ---------------- fused casts: all 5 weight/x tensors in one launch ----------------
__global__ void cast_all(const float* __restrict__ x, const float* __restrict__ Wq,
                         const float* __restrict__ Wkvu, const float* __restrict__ Wout,
                         const float* __restrict__ Wkvd,
                         ushort_t* __restrict__ xb, ushort_t* __restrict__ wq,
                         ushort_t* __restrict__ wkvu, ushort_t* __restrict__ wout,
                         ushort_t* __restrict__ wkvd) {
  int i = blockIdx.x * 256 + threadIdx.x;
  const float* src;
  ushort_t* dst;
  int j;
  if (i < 2097152) { src = x; dst = xb; j = i; }
  else if (i < 3145728) { src = Wq; dst = wq; j = i - 2097152; }
  else if (i < 3538944) { src = Wkvu; dst = wkvu; j = i - 3145728; }
  else if (i < 4587520) { src = Wout; dst = wout; j = i - 3538944; }
  else {
    j = i - 4587520;                      // wkvd with row pad 576->640
    int row = j >> 9, col4 = j & 511;
    ushort4 o;
    if (row < 576) {
      float4 v = ((const float4*)Wkvd)[row * 512 + col4];
      o.x = f2bf(v.x); o.y = f2bf(v.y); o.z = f2bf(v.z); o.w = f2bf(v.w);
    } else { o.x = 0; o.y = 0; o.z = 0; o.w = 0; }
    ((ushort4*)wkvd)[j] = o;
    return;
  }
  float4 v = ((const float4*)src)[j];
  ushort4 o;
  o.x = f2bf(v.x); o.y = f2bf(v.y); o.z = f2bf(v.z); o.w = f2bf(v.w);
  ((ushort4*)dst)[j] = o;
}

// ---------------- mask rearrange for 32x32 swapped layout ----------------
// ushort8 unit index u = q*256 + kt*8 + kblk*4 + half*2 + rr
// element j: value = mask[q][kt*64 + kblk*32 + 4*half + (j&3) + 8*(2*rr+(j>>2))] / ln2
__global__ void mask_rearrange(const float* __restrict__ mask, ushort_t* __restrict__ m4) {
  const float INVLN2 = 1.4426950408889634f;
  int i = blockIdx.x * 256 + threadIdx.x;   // 524288 units
  if (i >= 524288) return;
  int rr = i & 1, half = (i >> 1) & 1, kblk = (i >> 2) & 1, kt = (i >> 3) & 31, q = i >> 8;
  const float* src = mask + (size_t)q * 2048 + kt * 64 + kblk * 32 + half * 4 + rr * 16;
  float4 a = *(const float4*)src;         // j=0..3
  float4 c = *(const float4*)(src + 8);   // j=4..7
  ushort8v o;
  o[0] = f2bf(a.x * INVLN2); o[1] = f2bf(a.y * INVLN2);
  o[2] = f2bf(a.z * INVLN2); o[3] = f2bf(a.w * INVLN2);
  o[4] = f2bf(c.x * INVLN2); o[5] = f2bf(c.y * INVLN2);
  o[6] = f2bf(c.z * INVLN2); o[7] = f2bf(c.w * INVLN2);
  ((ushort8v*)m4)[i] = o;
}

// ---------------- GEMM: C[m][n] = sum_k A[m][k]*B[n][k], 128x128x32 tiles ----------------
template<int MODE>
__global__ __launch_bounds__(256, 2)
void gemm_bt(const ushort_t* __restrict__ A, int lda,
             const ushort_t* __restrict__ Bm, int ldb,
             void* __restrict__ Cout, int ldc,
             int M, int N, int K,
             char* __restrict__ vtb, char* __restrict__ kbuf)
{
  __shared__ __align__(16) ushort_t sA[128 * 32];
  __shared__ __align__(16) ushort_t sB[128 * 32];
  int tid = threadIdx.x;
  int nTn = N >> 7;
  int bid = blockIdx.x;
  int chunk = gridDim.x >> 3;                       // grids are %8==0 -> bijective
  bid = (bid & 7) * chunk + (bid >> 3);             // XCD-chunked swizzle
  int tm = bid / nTn, tn = bid - tm * nTn;
  int wave = tid >> 6, lane = tid & 63;
  int wm = (wave >> 1) << 6, wn = (wave & 1) << 6;
  int l16 = lane & 15, g16 = lane >> 4;
  f32x4 acc[4][4] = {};
  int srow = tid >> 2, scol = (tid & 3) << 3;
  const ushort_t* Ag = A + (size_t)(tm * 128 + srow) * lda + scol;
  const ushort_t* Bg = Bm + (size_t)(tn * 128 + srow) * ldb + scol;
  ushort_t* sAp = &sA[srow * 32 + scol];
  ushort_t* sBp = &sB[srow * 32 + scol];
  for (int kt = 0; kt < K; kt += 32) {
    gload16(Ag, sAp);
    gload16(Ag + (size_t)64 * lda, sAp + 64 * 32);
    gload16(Bg, sBp);
    gload16(Bg + (size_t)64 * ldb, sBp + 64 * 32);
    Ag += 32; Bg += 32;
    __syncthreads();
    bf16x8 af[4], bfr[4];
#pragma unroll
    for (int i = 0; i < 4; i++) af[i] = *(const bf16x8*)&sA[(wm + i * 16 + l16) * 32 + g16 * 8];
#pragma unroll
    for (int i = 0; i < 4; i++) bfr[i] = *(const bf16x8*)&sB[(wn + i * 16 + l16) * 32 + g16 * 8];
#pragma unroll
    for (int i = 0; i < 4; i++)
#pragma unroll
      for (int j = 0; j < 4; j++)
        acc[i][j] = MFMA16(af[i], bfr[j], acc[i][j], 0, 0, 0);
    __syncthreads();
  }
  // epilogue: C/D layout col=lane&15, row=(lane>>4)*4+r
#pragma unroll
  for (int i = 0; i < 4; i++) {
#pragma unroll
    for (int j = 0; j < 4; j++) {
#pragma unroll
      for (int r = 0; r < 4; r++) {
        int grow = tm * 128 + wm + i * 16 + g16 * 4 + r;
        int gcol = tn * 128 + wn + j * 16 + l16;
        float v = acc[i][j][r];
        if constexpr (MODE == 0) {
          ((ushort_t*)Cout)[(size_t)grow * ldc + gcol] = f2bf(v);
        } else if constexpr (MODE == 2) {
          ((float*)Cout)[(size_t)grow * ldc + gcol] = v;
        } else {
          int h = gcol / 192, jj = gcol - h * 192;
          int b = grow >> 11, s = grow & 2047;
          size_t bh = (size_t)(b * Hc + h);
          if (jj < 128) {
            // V^T, pre-swizzled for linear staging of 64-col tiles
            *(ushort_t*)(vtb + bh * 524288 + (size_t)jj * 4096 + ((s >> 6) * 128) +
                         ((2 * (s & 63)) ^ ((jj & 7) << 4))) = f2bf(v);
          } else {
            int col = 64 + (jj - 128);                    // nope -> k dims 64..127
            *(ushort_t*)(kbuf + (bh * Sc + s) * 256 + ((2 * col) ^ ((s & 7) << 4))) = f2bf(v);
          }
        }
      }
    }
  }
}

// ---------------- broadcast k_rope into kbuf (swizzled byte layout) ----------------
__global__ void rope_fill(const ushort_t* __restrict__ comp, char* __restrict__ kbuf) {
  int i = blockIdx.x * 256 + threadIdx.x;  // over B*S*8 16-byte blocks
  if (i >= Bc * Sc * 8) return;
  int blk = i & 7;
  int m = i >> 3;
  int s = m & 2047, b = m >> 11;
  uint4 v = *(const uint4*)&comp[(size_t)m * 640 + 512 + blk * 8];
  int off = (blk * 16) ^ ((s & 7) << 4);
#pragma unroll
  for (int h = 0; h < Hc; h++) {
    *(uint4*)(kbuf + ((size_t)(b * Hc + h) * Sc + s) * 256 + off) = v;
  }
}

// ---------------- flash attention: 32x32 MFMA, 2 q-blocks/wave (operand reuse) ----------------
// block = 128 threads = 2 waves; wave owns 64 q-rows (2 x 32-col blocks); q-tile 128.
// Each K/V fragment read feeds TWO MFMAs -> ds_read per MFMA = 0.5 (was 1.0).
// Single 32KB LDS buffer; per-kblk in-register softmax; grid 512.
__global__ __launch_bounds__(128, 1)
void attn_kernel(const ushort_t* __restrict__ qb, const char* __restrict__ kbuf,
                 const char* __restrict__ vtb, const ushort_t* __restrict__ m4,
                 ushort_t* __restrict__ attn_o)
{
  __shared__ __align__(16) char smem[32768];
  char* sK = smem;            // 16KB: 64 k-rows x 256B (swizzled)
  char* sV = smem + 16384;    // 16KB: 128 vd-rows x 128B (swizzled)
  const float scale2 = 0.12752081738040466f;  // 128^-0.5 / ln2
  int bid = blockIdx.x;
  bid = (bid & 7) * 64 + (bid >> 3);         // XCD-chunked swizzle (512 % 8 == 0)
  int qt = bid & 15, bh = bid >> 4;
  int b = bh >> 4, h = bh & 15;
  int tid = threadIdx.x, wave = tid >> 6, lane = tid & 63;
  int l32 = lane & 31, half = lane >> 5;
  int sx = (l32 & 7) << 4;
  int qbase = qt * 128 + wave * 64;

  // Q fragments for both q-blocks (B-operand: col = q, k = ks*16 + half*8 + e)
  bf16x8 qf0[8], qf1[8];
  {
    const ushort_t* qp0 = qb + (size_t)(b * Sc + qbase + l32) * 2048 + h * 128 + half * 8;
    const ushort_t* qp1 = qp0 + (size_t)32 * 2048;
#pragma unroll
    for (int ks = 0; ks < 8; ks++) {
      qf0[ks] = *(const bf16x8*)(qp0 + ks * 16);
      qf1[ks] = *(const bf16x8*)(qp1 + ks * 16);
    }
  }

  float mrun0 = -3.0e38f, lrun0 = 0.f;   // q = qbase + l32
  float mrun1 = -3.0e38f, lrun1 = 0.f;   // q = qbase + 32 + l32
  f32x16 acc0[4] = {}, acc1[4] = {};     // [vdblk]; rows = q reg-pattern, col = vd

  const char* kg = kbuf + (size_t)bh * 524288;
  const char* vg = vtb + (size_t)bh * 524288;
  const ushort8v* mqb = (const ushort8v*)m4;
  size_t mo0 = (size_t)(qbase + l32) * 256 + half * 2;
  size_t mo1 = mo0 + (size_t)32 * 256;

  for (int kt = 0; kt < 32; kt++) {
    // stage K tile: 16KB linear (global bytes pre-swizzled)
#pragma unroll
    for (int it = 0; it < 8; it++)
      gload16(kg + kt * 16384 + it * 2048 + tid * 16, sK + it * 2048 + tid * 16);
    // stage V^T tile: 16KB, per-vd-row 128B chunks (global bytes pre-swizzled)
#pragma unroll
    for (int it = 0; it < 8; it++) {
      int l = it * 2048 + tid * 16;
      gload16(vg + (size_t)(l >> 7) * 4096 + kt * 128 + (l & 127), sV + l);
    }
    __syncthreads();

#pragma unroll
    for (int kblk = 0; kblk < 2; kblk++) {
      // mask fragments (4 x 16B global loads, issue early; hide under MFMA)
      ushort8v mv00 = mqb[mo0 + kt * 8 + kblk * 4 + 0];
      ushort8v mv01 = mqb[mo0 + kt * 8 + kblk * 4 + 1];
      ushort8v mv10 = mqb[mo1 + kt * 8 + kblk * 4 + 0];
      ushort8v mv11 = mqb[mo1 + kt * 8 + kblk * 4 + 1];

      // QK^T (swapped): each kfr read feeds both q-blocks
      f32x16 sc0 = {}, sc1 = {};
      __builtin_amdgcn_s_setprio(1);
#pragma unroll
      for (int ks = 0; ks < 8; ks++) {
        bf16x8 kfr = *(const bf16x8*)(sK + (kblk * 32 + l32) * 256 +
                                      ((ks * 32 + half * 16) ^ sx));
        sc0 = MFMA32(kfr, qf0[ks], sc0, 0, 0, 0);
        sc1 = MFMA32(kfr, qf1[ks], sc1, 0, 0, 0);
      }
      __builtin_amdgcn_s_setprio(0);

      // lane-local softmax (k = (r&3)+8*(r>>2)+4*half + kblk*32 within tile)
#pragma unroll
      for (int r = 0; r < 16; r++) {
        sc0[r] = sc0[r] * scale2 + bf2f((r < 8 ? mv00 : mv01)[r & 7]);
        sc1[r] = sc1[r] * scale2 + bf2f((r < 8 ? mv10 : mv11)[r & 7]);
      }
      float mx0 = sc0[0], mx1 = sc1[0];
#pragma unroll
      for (int r = 1; r < 16; r++) { mx0 = fmaxf(mx0, sc0[r]); mx1 = fmaxf(mx1, sc1[r]); }
      mx0 = fmaxf(mx0, __shfl_xor(mx0, 32));
      mx1 = fmaxf(mx1, __shfl_xor(mx1, 32));
      bool ok = (mx0 <= mrun0 + 11.0f) & (mx1 <= mrun1 + 11.0f);
      if (!__all(ok)) {                     // T13 defer-max (rare)
        float mnew0 = fmaxf(mrun0, mx0), mnew1 = fmaxf(mrun1, mx1);
        float corr0 = __builtin_amdgcn_exp2f(mrun0 - mnew0);
        float corr1 = __builtin_amdgcn_exp2f(mrun1 - mnew1);
        lrun0 *= corr0; mrun0 = mnew0;
        lrun1 *= corr1; mrun1 = mnew1;
#pragma unroll
        for (int r = 0; r < 16; r++) {
          int rowq = (r & 3) + 8 * (r >> 2) + 4 * half;
          float cr0 = __shfl(corr0, rowq);
          float cr1 = __shfl(corr1, rowq);
#pragma unroll
          for (int vb = 0; vb < 4; vb++) { acc0[vb][r] *= cr0; acc1[vb][r] *= cr1; }
        }
      }
      // exp + pack to PV A-frags (in-register, permlane32_swap redistribution)
      bf16x8 pf0[2], pf1[2];
      {
        float rs = 0.f;
        uint32_t W[8];
#pragma unroll
        for (int m = 0; m < 4; m++) {
          float p0 = __builtin_amdgcn_exp2f(sc0[4 * m + 0] - mrun0);
          float p1 = __builtin_amdgcn_exp2f(sc0[4 * m + 1] - mrun0);
          float p2 = __builtin_amdgcn_exp2f(sc0[4 * m + 2] - mrun0);
          float p3 = __builtin_amdgcn_exp2f(sc0[4 * m + 3] - mrun0);
          rs += (p0 + p1) + (p2 + p3);
          W[2 * m] = cvtpk(p0, p1); W[2 * m + 1] = cvtpk(p2, p3);
        }
        lrun0 += rs;
#pragma unroll
        for (int k2 = 0; k2 < 2; k2++) {
          uint32_t a0 = W[4 * k2 + 0], a1 = W[4 * k2 + 1];
          uint32_t b0 = W[4 * k2 + 2], b1 = W[4 * k2 + 3];
          plswap(a0, b0); plswap(a1, b1);
          u32x4 t; t[0] = a0; t[1] = a1; t[2] = b0; t[3] = b1;
          pf0[k2] = __builtin_bit_cast(bf16x8, t);
        }
      }
      {
        float rs = 0.f;
        uint32_t W[8];
#pragma unroll
        for (int m = 0; m < 4; m++) {
          float p0 = __builtin_amdgcn_exp2f(sc1[4 * m + 0] - mrun1);
          float p1 = __builtin_amdgcn_exp2f(sc1[4 * m + 1] - mrun1);
          float p2 = __builtin_amdgcn_exp2f(sc1[4 * m + 2] - mrun1);
          float p3 = __builtin_amdgcn_exp2f(sc1[4 * m + 3] - mrun1);
          rs += (p0 + p1) + (p2 + p3);
          W[2 * m] = cvtpk(p0, p1); W[2 * m + 1] = cvtpk(p2, p3);
        }
        lrun1 += rs;
#pragma unroll
        for (int k2 = 0; k2 < 2; k2++) {
          uint32_t a0 = W[4 * k2 + 0], a1 = W[4 * k2 + 1];
          uint32_t b0 = W[4 * k2 + 2], b1 = W[4 * k2 + 3];
          plswap(a0, b0); plswap(a1, b1);
          u32x4 t; t[0] = a0; t[1] = a1; t[2] = b0; t[3] = b1;
          pf1[k2] = __builtin_bit_cast(bf16x8, t);
        }
      }

      // PV: each vf read feeds both q-blocks
      __builtin_amdgcn_s_setprio(1);
#pragma unroll
      for (int k2 = 0; k2 < 2; k2++)
#pragma unroll
        for (int vb = 0; vb < 4; vb++) {
          bf16x8 vf = *(const bf16x8*)(sV + (vb * 32 + l32) * 128 +
                                       ((kblk * 64 + k2 * 32 + half * 16) ^ sx));
          acc0[vb] = MFMA32(pf0[k2], vf, acc0[vb], 0, 0, 0);
          acc1[vb] = MFMA32(pf1[k2], vf, acc1[vb], 0, 0, 0);
        }
      __builtin_amdgcn_s_setprio(0);
    }

    __syncthreads();   // all waves done reading sK/sV before next stage
  }

  // epilogue: combine half-partial l, divide, store both q-blocks
  lrun0 += __shfl_xor(lrun0, 32);
  lrun1 += __shfl_xor(lrun1, 32);
#pragma unroll
  for (int r = 0; r < 16; r++) {
    int rowq = (r & 3) + 8 * (r >> 2) + 4 * half;
    float inv0 = 1.0f / __shfl(lrun0, rowq);
    float inv1 = 1.0f / __shfl(lrun1, rowq);
    ushort_t* op0 = attn_o + (size_t)(b * Sc + qbase + rowq) * 2048 + h * 128 + l32;
    ushort_t* op1 = op0 + (size_t)32 * 2048;
#pragma unroll
    for (int vb = 0; vb < 4; vb++) {
      op0[vb * 32] = f2bf(acc0[vb][r] * inv0);
      op1[vb * 32] = f2bf(acc1[vb][r] * inv1);
    }
  }
}

extern "C" void kernel_launch(void* const* d_in, const int* in_sizes, int n_in,
                              void* d_out, int out_size, void* d_ws, size_t ws_size,
                              hipStream_t stream) {
  const float* x    = (const float*)d_in[0];
  const float* mask = (const float*)d_in[1];
  const float* Wkvd = (const float*)d_in[2];
  const float* Wkvu = (const float*)d_in[3];
  const float* Wq   = (const float*)d_in[4];
  const float* Wout = (const float*)d_in[5];

  char* ws = (char*)d_ws;
  size_t off = 0;
  auto alloc = [&](size_t bytes) { char* p = ws + off; off += (bytes + 255) & ~(size_t)255; return p; };
  ushort_t* xb   = (ushort_t*)alloc((size_t)4096 * 2048 * 2);
  ushort_t* wkvd = (ushort_t*)alloc((size_t)640 * 2048 * 2);
  ushort_t* wq   = (ushort_t*)alloc((size_t)2048 * 2048 * 2);
  ushort_t* wkvu = (ushort_t*)alloc((size_t)3072 * 512 * 2);
  ushort_t* wout = (ushort_t*)alloc((size_t)2048 * 2048 * 2);
  ushort_t* comp = (ushort_t*)alloc((size_t)4096 * 640 * 2);
  ushort_t* qbuf = (ushort_t*)alloc((size_t)4096 * 2048 * 2);
  char*     kbuf = alloc((size_t)Bc * Hc * Sc * 256);
  char*     vtb  = alloc((size_t)Bc * Hc * 524288);
  ushort_t* attn_o = xb;   // xb dead after q-GEMM; reuse
  ushort_t* m4 = wq;       // wq dead after q-GEMM; reuse (8MB)

  // all casts in one launch
  cast_all<<<19200, 256, 0, stream>>>(x, Wq, Wkvu, Wout, Wkvd, xb, wq, wkvu, wout, wkvd);

  // compressed = x . W_kv_down^T  (N padded 576->640)
  gemm_bt<0><<<32 * 5, 256, 0, stream>>>(xb, 2048, wkvd, 2048, comp, 640, 4096, 640, 2048, nullptr, nullptr);
  // q = x . W_q^T
  gemm_bt<0><<<32 * 16, 256, 0, stream>>>(xb, 2048, wq, 2048, qbuf, 2048, 4096, 2048, 2048, nullptr, nullptr);
  // mask -> 32x32 swapped fragment order bf16 * (1/ln2)  (after q-GEMM: m4 overlays wq)
  mask_rearrange<<<2048, 256, 0, stream>>>(mask, m4);
  // kv_exp = kv_c . W_kv_up^T, scattered into vT(swizzled) + kbuf(nope, swizzled)
  gemm_bt<1><<<32 * 24, 256, 0, stream>>>(comp, 640, wkvu, 512, nullptr, 0, 4096, 3072, 512, vtb, kbuf);
  // k_rope broadcast into kbuf (swizzled)
  rope_fill<<<32768 / 256, 256, 0, stream>>>(comp, kbuf);
  // flash attention (32x32 MFMA, 2 q-blocks/wave, in-register P)
  attn_kernel<<<512, 128, 0, stream>>>(qbuf, kbuf, vtb, m4, attn_o);
  // out = attn . W_out^T (fp32 store)
  gemm_bt<2><<<32 * 16, 256, 0, stream>>>(attn_o, 2048, wout, 2048, d_out, 2048, 4096, 2048, 2048, nullptr, nullptr);
}

// Round 9
// 262.929 us; speedup vs baseline: 1.1833x; 1.1392x over previous
//
#include <hip/hip_runtime.h>
#include <hip/hip_bf16.h>
#include <stdint.h>

typedef __bf16 bf16x8 __attribute__((ext_vector_type(8)));
typedef float f32x4 __attribute__((ext_vector_type(4)));
typedef float f32x16 __attribute__((ext_vector_type(16)));
typedef uint32_t u32x4 __attribute__((ext_vector_type(4)));
typedef unsigned short ushort_t;
typedef unsigned short ushort8v __attribute__((ext_vector_type(8)));

#define MFMA16 __builtin_amdgcn_mfma_f32_16x16x32_bf16
#define MFMA32 __builtin_amdgcn_mfma_f32_32x32x16_bf16

static constexpr int Bc = 2, Sc = 2048, Ec = 2048, Hc = 16;

__device__ __forceinline__ void gload16(const void* g, void* l) {
  __builtin_amdgcn_global_load_lds(
      (const __attribute__((address_space(1))) void*)g,
      (__attribute__((address_space(3))) void*)l, 16, 0, 0);
}

__device__ __forceinline__ ushort_t f2bf(float f) {
  uint32_t u = __float_as_uint(f);
  uint32_t r = (u + 0x7fffu + ((u >> 16) & 1u)) >> 16;
  return (ushort_t)r;
}
__device__ __forceinline__ float bf2f(ushort_t u) {
  return __uint_as_float((uint32_t)u << 16);
}
__device__ __forceinline__ uint32_t cvtpk(float a, float b) {
  uint32_t d;
  asm("v_cvt_pk_bf16_f32 %0, %1, %2" : "=v"(d) : "v"(a), "v"(b));
  return d;
}
// exchange: a[lanes 32..63] <-> b[lanes 0..31]
__device__ __forceinline__ void plswap(uint32_t& a, uint32_t& b) {
  asm("v_permlane32_swap_b32 %0, %1" : "+v"(a), "+v"(b));
}

// ---------------- fused casts: all 5 weight/x tensors in one launch ----------------
__global__ void cast_all(const float* __restrict__ x, const float* __restrict__ Wq,
                         const float* __restrict__ Wkvu, const float* __restrict__ Wout,
                         const float* __restrict__ Wkvd,
                         ushort_t* __restrict__ xb, ushort_t* __restrict__ wq,
                         ushort_t* __restrict__ wkvu, ushort_t* __restrict__ wout,
                         ushort_t* __restrict__ wkvd) {
  int i = blockIdx.x * 256 + threadIdx.x;
  const float* src;
  ushort_t* dst;
  int j;
  if (i < 2097152) { src = x; dst = xb; j = i; }
  else if (i < 3145728) { src = Wq; dst = wq; j = i - 2097152; }
  else if (i < 3538944) { src = Wkvu; dst = wkvu; j = i - 3145728; }
  else if (i < 4587520) { src = Wout; dst = wout; j = i - 3538944; }
  else {
    j = i - 4587520;                      // wkvd with row pad 576->640
    int row = j >> 9, col4 = j & 511;
    ushort4 o;
    if (row < 576) {
      float4 v = ((const float4*)Wkvd)[row * 512 + col4];
      o.x = f2bf(v.x); o.y = f2bf(v.y); o.z = f2bf(v.z); o.w = f2bf(v.w);
    } else { o.x = 0; o.y = 0; o.z = 0; o.w = 0; }
    ((ushort4*)wkvd)[j] = o;
    return;
  }
  float4 v = ((const float4*)src)[j];
  ushort4 o;
  o.x = f2bf(v.x); o.y = f2bf(v.y); o.z = f2bf(v.z); o.w = f2bf(v.w);
  ((ushort4*)dst)[j] = o;
}

// ---------------- mask rearrange for 32x32 swapped layout ----------------
// ushort8 unit index u = q*256 + kt*8 + kblk*4 + half*2 + rr
// element j: value = mask[q][kt*64 + kblk*32 + 4*half + (j&3) + 8*(2*rr+(j>>2))] / ln2
__global__ void mask_rearrange(const float* __restrict__ mask, ushort_t* __restrict__ m4) {
  const float INVLN2 = 1.4426950408889634f;
  int i = blockIdx.x * 256 + threadIdx.x;   // 524288 units
  if (i >= 524288) return;
  int rr = i & 1, half = (i >> 1) & 1, kblk = (i >> 2) & 1, kt = (i >> 3) & 31, q = i >> 8;
  const float* src = mask + (size_t)q * 2048 + kt * 64 + kblk * 32 + half * 4 + rr * 16;
  float4 a = *(const float4*)src;         // j=0..3
  float4 c = *(const float4*)(src + 8);   // j=4..7
  ushort8v o;
  o[0] = f2bf(a.x * INVLN2); o[1] = f2bf(a.y * INVLN2);
  o[2] = f2bf(a.z * INVLN2); o[3] = f2bf(a.w * INVLN2);
  o[4] = f2bf(c.x * INVLN2); o[5] = f2bf(c.y * INVLN2);
  o[6] = f2bf(c.z * INVLN2); o[7] = f2bf(c.w * INVLN2);
  ((ushort8v*)m4)[i] = o;
}

// ---------------- GEMM: C[m][n] = sum_k A[m][k]*B[n][k], 128x128 tiles, BK=64 ----------------
// K staged as two [128][32] slices per barrier period -> half the barrier/drain count of BK=32.
template<int MODE>
__global__ __launch_bounds__(256, 2)
void gemm_bt(const ushort_t* __restrict__ A, int lda,
             const ushort_t* __restrict__ Bm, int ldb,
             void* __restrict__ Cout, int ldc,
             int M, int N, int K,
             char* __restrict__ vtb, char* __restrict__ kbuf)
{
  __shared__ __align__(16) ushort_t sA[2][128 * 32];
  __shared__ __align__(16) ushort_t sB[2][128 * 32];
  int tid = threadIdx.x;
  int nTn = N >> 7;
  int bid = blockIdx.x;
  int chunk = gridDim.x >> 3;                       // grids are %8==0 -> bijective
  bid = (bid & 7) * chunk + (bid >> 3);             // XCD-chunked swizzle
  int tm = bid / nTn, tn = bid - tm * nTn;
  int wave = tid >> 6, lane = tid & 63;
  int wm = (wave >> 1) << 6, wn = (wave & 1) << 6;
  int l16 = lane & 15, g16 = lane >> 4;
  f32x4 acc[4][4] = {};
  int srow = tid >> 2, scol = (tid & 3) << 3;
  const ushort_t* Ag = A + (size_t)(tm * 128 + srow) * lda + scol;
  const ushort_t* Bg = Bm + (size_t)(tn * 128 + srow) * ldb + scol;
  ushort_t* sA0 = &sA[0][srow * 32 + scol];
  ushort_t* sA1 = &sA[1][srow * 32 + scol];
  ushort_t* sB0 = &sB[0][srow * 32 + scol];
  ushort_t* sB1 = &sB[1][srow * 32 + scol];
  for (int kt = 0; kt < K; kt += 64) {
    gload16(Ag, sA0);
    gload16(Ag + (size_t)64 * lda, sA0 + 64 * 32);
    gload16(Ag + 32, sA1);
    gload16(Ag + (size_t)64 * lda + 32, sA1 + 64 * 32);
    gload16(Bg, sB0);
    gload16(Bg + (size_t)64 * ldb, sB0 + 64 * 32);
    gload16(Bg + 32, sB1);
    gload16(Bg + (size_t)64 * ldb + 32, sB1 + 64 * 32);
    Ag += 64; Bg += 64;
    __syncthreads();
#pragma unroll
    for (int h2 = 0; h2 < 2; h2++) {
      bf16x8 af[4], bfr[4];
#pragma unroll
      for (int i = 0; i < 4; i++) af[i] = *(const bf16x8*)&sA[h2][(wm + i * 16 + l16) * 32 + g16 * 8];
#pragma unroll
      for (int i = 0; i < 4; i++) bfr[i] = *(const bf16x8*)&sB[h2][(wn + i * 16 + l16) * 32 + g16 * 8];
#pragma unroll
      for (int i = 0; i < 4; i++)
#pragma unroll
        for (int j = 0; j < 4; j++)
          acc[i][j] = MFMA16(af[i], bfr[j], acc[i][j], 0, 0, 0);
    }
    __syncthreads();
  }
  // epilogue: C/D layout col=lane&15, row=(lane>>4)*4+r
#pragma unroll
  for (int i = 0; i < 4; i++) {
#pragma unroll
    for (int j = 0; j < 4; j++) {
      int grow0 = tm * 128 + wm + i * 16 + g16 * 4;
      int gcol = tn * 128 + wn + j * 16 + l16;
      if constexpr (MODE == 0) {
#pragma unroll
        for (int r = 0; r < 4; r++)
          ((ushort_t*)Cout)[(size_t)(grow0 + r) * ldc + gcol] = f2bf(acc[i][j][r]);
      } else if constexpr (MODE == 2) {
#pragma unroll
        for (int r = 0; r < 4; r++)
          ((float*)Cout)[(size_t)(grow0 + r) * ldc + gcol] = acc[i][j][r];
      } else {
        int h = gcol / 192, jj = gcol - h * 192;
        int b = grow0 >> 11, s0 = grow0 & 2047;
        size_t bh = (size_t)(b * Hc + h);
        if (jj < 128) {
          // V^T, pre-swizzled; 4 consecutive s -> one 8B store (s0 %4==0, same 64-chunk)
          ushort4 pk;
          pk.x = f2bf(acc[i][j][0]); pk.y = f2bf(acc[i][j][1]);
          pk.z = f2bf(acc[i][j][2]); pk.w = f2bf(acc[i][j][3]);
          *(ushort4*)(vtb + bh * 524288 + (size_t)jj * 4096 + ((s0 >> 6) * 128) +
                      ((2 * (s0 & 63)) ^ ((jj & 7) << 4))) = pk;
        } else {
          int col = 64 + (jj - 128);                    // nope -> k dims 64..127
#pragma unroll
          for (int r = 0; r < 4; r++) {
            int s = s0 + r;
            *(ushort_t*)(kbuf + (bh * Sc + s) * 256 + ((2 * col) ^ ((s & 7) << 4))) = f2bf(acc[i][j][r]);
          }
        }
      }
    }
  }
}

// ---------------- broadcast k_rope into kbuf (swizzled byte layout) ----------------
__global__ void rope_fill(const ushort_t* __restrict__ comp, char* __restrict__ kbuf) {
  int i = blockIdx.x * 256 + threadIdx.x;  // over B*S*8 16-byte blocks
  if (i >= Bc * Sc * 8) return;
  int blk = i & 7;
  int m = i >> 3;
  int s = m & 2047, b = m >> 11;
  uint4 v = *(const uint4*)&comp[(size_t)m * 640 + 512 + blk * 8];
  int off = (blk * 16) ^ ((s & 7) << 4);
#pragma unroll
  for (int h = 0; h < Hc; h++) {
    *(uint4*)(kbuf + ((size_t)(b * Hc + h) * Sc + s) * 256 + off) = v;
  }
}

// ---------------- flash attention, 32x32 MFMA + swapped QK^T + in-register P ----------------
// block = 128 threads = 2 waves x 32 q-rows (q-tile 64); KVBLK=64; LDS 32KB. (round-6 verbatim)
__global__ __launch_bounds__(128, 2)
void attn_kernel(const ushort_t* __restrict__ qb, const char* __restrict__ kbuf,
                 const char* __restrict__ vtb, const ushort_t* __restrict__ m4,
                 ushort_t* __restrict__ attn_o)
{
  __shared__ __align__(16) char smem[32768];
  char* sK = smem;            // 16KB: 64 k-rows x 256B (swizzled)
  char* sV = smem + 16384;    // 16KB: 128 vd-rows x 128B (swizzled)
  const float scale2 = 0.12752081738040466f;  // 128^-0.5 / ln2
  int bid = blockIdx.x;
  bid = (bid & 7) * 128 + (bid >> 3);        // XCD-chunked swizzle (1024 % 8 == 0)
  int qt = bid & 31, bh = bid >> 5;
  int b = bh >> 4, h = bh & 15;
  int tid = threadIdx.x, wave = tid >> 6, lane = tid & 63;
  int l32 = lane & 31, half = lane >> 5;
  int sx = (l32 & 7) << 4;
  int qbase = qt * 64 + wave * 32;

  // Q fragments (B-operand): col = q = l32, k = ks*16 + half*8 + e
  bf16x8 qf[8];
  {
    const ushort_t* qp = qb + (size_t)(b * Sc + qbase + l32) * 2048 + h * 128 + half * 8;
#pragma unroll
    for (int ks = 0; ks < 8; ks++) qf[ks] = *(const bf16x8*)(qp + ks * 16);
  }

  float mrun = -3.0e38f, lrun = 0.f;   // per-lane scalars for q = qbase + l32
  f32x16 acco[4] = {};                  // [vdblk]; rows = q reg-pattern, col = vd

  const char* kg = kbuf + (size_t)bh * 524288;
  const char* vg = vtb + (size_t)bh * 524288;
  const ushort8v* mq = (const ushort8v*)m4 + (size_t)(qbase + l32) * 256 + half * 2;

  for (int kt = 0; kt < 32; kt++) {
    // stage K tile: 16KB linear (global bytes pre-swizzled)
#pragma unroll
    for (int it = 0; it < 8; it++)
      gload16(kg + kt * 16384 + it * 2048 + tid * 16, sK + it * 2048 + tid * 16);
    // stage V^T tile: 16KB, per-vd-row 128B chunks (global bytes pre-swizzled)
#pragma unroll
    for (int it = 0; it < 8; it++) {
      int l = it * 2048 + tid * 16;
      gload16(vg + (size_t)(l >> 7) * 4096 + kt * 128 + (l & 127), sV + l);
    }
    // mask fragments for this tile (4 x 16B, coalesced; latency hides under stage)
    ushort8v mvv[4];
#pragma unroll
    for (int kb = 0; kb < 2; kb++)
#pragma unroll
      for (int rr = 0; rr < 2; rr++)
        mvv[kb * 2 + rr] = mq[kt * 8 + kb * 4 + rr];
    __syncthreads();

#pragma unroll
    for (int kblk = 0; kblk < 2; kblk++) {
      // QK^T (swapped): sc rows = k (32), cols = q (32)
      f32x16 sc = {};
      __builtin_amdgcn_s_setprio(1);
#pragma unroll
      for (int ks = 0; ks < 8; ks++) {
        bf16x8 kfr = *(const bf16x8*)(sK + (kblk * 32 + l32) * 256 +
                                      ((ks * 32 + half * 16) ^ sx));
        sc = MFMA32(kfr, qf[ks], sc, 0, 0, 0);
      }
      __builtin_amdgcn_s_setprio(0);

      // lane-local softmax: lane holds P[q=l32][k = (r&3)+8*(r>>2)+4*half + kblk*32]
#pragma unroll
      for (int r = 0; r < 16; r++)
        sc[r] = sc[r] * scale2 + bf2f(mvv[kblk * 2 + (r >> 3)][r & 7]);
      float mx = sc[0];
#pragma unroll
      for (int r = 1; r < 16; r++) mx = fmaxf(mx, sc[r]);
      mx = fmaxf(mx, __shfl_xor(mx, 32));
      if (!__all(mx <= mrun + 11.0f)) {       // T13 defer-max (rare)
        float mnew = fmaxf(mrun, mx);
        float corr = __builtin_amdgcn_exp2f(mrun - mnew);
        lrun *= corr; mrun = mnew;
#pragma unroll
        for (int r = 0; r < 16; r++) {
          float cr = __shfl(corr, (r & 3) + 8 * (r >> 2) + 4 * half);
#pragma unroll
          for (int vb = 0; vb < 4; vb++) acco[vb][r] *= cr;
        }
      }
      float rs = 0.f;
      uint32_t W[8];
#pragma unroll
      for (int m = 0; m < 4; m++) {
        float p0 = __builtin_amdgcn_exp2f(sc[4 * m + 0] - mrun);
        float p1 = __builtin_amdgcn_exp2f(sc[4 * m + 1] - mrun);
        float p2 = __builtin_amdgcn_exp2f(sc[4 * m + 2] - mrun);
        float p3 = __builtin_amdgcn_exp2f(sc[4 * m + 3] - mrun);
        rs += (p0 + p1) + (p2 + p3);
        W[2 * m] = cvtpk(p0, p1);
        W[2 * m + 1] = cvtpk(p2, p3);
      }
      lrun += rs;   // lane-partial (this half's k); combined in epilogue

      // redistribute P to PV A-frag layout: frag[k2] k = k2*16 + half*8 + e
      bf16x8 pf[2];
#pragma unroll
      for (int k2 = 0; k2 < 2; k2++) {
        uint32_t a0 = W[4 * k2 + 0], a1 = W[4 * k2 + 1];
        uint32_t b0 = W[4 * k2 + 2], b1 = W[4 * k2 + 3];
        plswap(a0, b0);
        plswap(a1, b1);
        u32x4 t; t[0] = a0; t[1] = a1; t[2] = b0; t[3] = b1;
        pf[k2] = __builtin_bit_cast(bf16x8, t);
      }

      // PV: acco[vb] += P(32q x 32k) . V(32k x 128vd)
      __builtin_amdgcn_s_setprio(1);
#pragma unroll
      for (int k2 = 0; k2 < 2; k2++)
#pragma unroll
        for (int vb = 0; vb < 4; vb++) {
          bf16x8 vf = *(const bf16x8*)(sV + (vb * 32 + l32) * 128 +
                                       ((kblk * 64 + k2 * 32 + half * 16) ^ sx));
          acco[vb] = MFMA32(pf[k2], vf, acco[vb], 0, 0, 0);
        }
      __builtin_amdgcn_s_setprio(0);
    }

    __syncthreads();   // all waves done reading sK/sV before next stage
  }

  // epilogue: combine half-partial l, divide, store
  lrun += __shfl_xor(lrun, 32);
#pragma unroll
  for (int r = 0; r < 16; r++) {
    int rowq = (r & 3) + 8 * (r >> 2) + 4 * half;
    float lr = __shfl(lrun, rowq);
    float inv = 1.0f / lr;
    int qrow = qbase + rowq;
    ushort_t* op = attn_o + (size_t)(b * Sc + qrow) * 2048 + h * 128 + l32;
#pragma unroll
    for (int vb = 0; vb < 4; vb++)
      op[vb * 32] = f2bf(acco[vb][r] * inv);
  }
}

extern "C" void kernel_launch(void* const* d_in, const int* in_sizes, int n_in,
                              void* d_out, int out_size, void* d_ws, size_t ws_size,
                              hipStream_t stream) {
  const float* x    = (const float*)d_in[0];
  const float* mask = (const float*)d_in[1];
  const float* Wkvd = (const float*)d_in[2];
  const float* Wkvu = (const float*)d_in[3];
  const float* Wq   = (const float*)d_in[4];
  const float* Wout = (const float*)d_in[5];

  char* ws = (char*)d_ws;
  size_t off = 0;
  auto alloc = [&](size_t bytes) { char* p = ws + off; off += (bytes + 255) & ~(size_t)255; return p; };
  ushort_t* xb   = (ushort_t*)alloc((size_t)4096 * 2048 * 2);
  ushort_t* wkvd = (ushort_t*)alloc((size_t)640 * 2048 * 2);
  ushort_t* wq   = (ushort_t*)alloc((size_t)2048 * 2048 * 2);
  ushort_t* wkvu = (ushort_t*)alloc((size_t)3072 * 512 * 2);
  ushort_t* wout = (ushort_t*)alloc((size_t)2048 * 2048 * 2);
  ushort_t* comp = (ushort_t*)alloc((size_t)4096 * 640 * 2);
  ushort_t* qbuf = (ushort_t*)alloc((size_t)4096 * 2048 * 2);
  char*     kbuf = alloc((size_t)Bc * Hc * Sc * 256);
  char*     vtb  = alloc((size_t)Bc * Hc * 524288);
  ushort_t* attn_o = xb;   // xb dead after q-GEMM; reuse
  ushort_t* m4 = wq;       // wq dead after q-GEMM; reuse (8MB)

  // all casts in one launch
  cast_all<<<19200, 256, 0, stream>>>(x, Wq, Wkvu, Wout, Wkvd, xb, wq, wkvu, wout, wkvd);

  // compressed = x . W_kv_down^T  (N padded 576->640)
  gemm_bt<0><<<32 * 5, 256, 0, stream>>>(xb, 2048, wkvd, 2048, comp, 640, 4096, 640, 2048, nullptr, nullptr);
  // q = x . W_q^T
  gemm_bt<0><<<32 * 16, 256, 0, stream>>>(xb, 2048, wq, 2048, qbuf, 2048, 4096, 2048, 2048, nullptr, nullptr);
  // mask -> 32x32 swapped fragment order bf16 * (1/ln2)  (after q-GEMM: m4 overlays wq)
  mask_rearrange<<<2048, 256, 0, stream>>>(mask, m4);
  // kv_exp = kv_c . W_kv_up^T, scattered into vT(swizzled) + kbuf(nope, swizzled)
  gemm_bt<1><<<32 * 24, 256, 0, stream>>>(comp, 640, wkvu, 512, nullptr, 0, 4096, 3072, 512, vtb, kbuf);
  // k_rope broadcast into kbuf (swizzled)
  rope_fill<<<32768 / 256, 256, 0, stream>>>(comp, kbuf);
  // flash attention (round-6 structure: 32x32 MFMA, in-register P, grid 1024 x 128 thr)
  attn_kernel<<<1024, 128, 0, stream>>>(qbuf, kbuf, vtb, m4, attn_o);
  // out = attn . W_out^T (fp32 store)
  gemm_bt<2><<<32 * 16, 256, 0, stream>>>(attn_o, 2048, wout, 2048, d_out, 2048, 4096, 2048, 2048, nullptr, nullptr);
}